// Round 1
// baseline (806.081 us; speedup 1.0000x reference)
//
#include <hip/hip_runtime.h>
#include <hip/hip_bf16.h>

#define B_ 2048
#define T_ 64
#define H_ 256
#define V_ 51
#define Z_ 32
#define K_ 1000

typedef __bf16 bf16x8 __attribute__((ext_vector_type(8)));
typedef float floatx4 __attribute__((ext_vector_type(4)));

__device__ inline unsigned short f2bf(float f){
    unsigned int u = __float_as_uint(f);
    u += 0x7fffu + ((u >> 16) & 1u);
    return (unsigned short)(u >> 16);
}
__device__ inline float sigm(float x){ return 1.0f/(1.0f+__expf(-x)); }
__device__ inline float tanh_fast(float x){
    x = fminf(fmaxf(x, -15.0f), 15.0f);
    float e = __expf(-2.0f*x);
    return (1.0f-e)/(1.0f+e);
}

// ---------------- prep kernels ----------------
// table_enc[v][g] = enc_emb[v]·enc_wih[g] + enc_bih[g]
// table_dec[v][g] = dec_emb[v]·dec_wih[g, 64:128] + dec_bih[g]
__global__ __launch_bounds__(256) void k_tables(
    const float* __restrict__ enc_emb, const float* __restrict__ enc_wih, const float* __restrict__ enc_bih,
    const float* __restrict__ dec_emb, const float* __restrict__ dec_wih, const float* __restrict__ dec_bih,
    float* __restrict__ te, float* __restrict__ td)
{
    int id = blockIdx.x*256 + threadIdx.x;
    if (id >= 2*V_*768) return;
    int which = id / (V_*768), r = id % (V_*768);
    int v = r / 768, g = r % 768;
    if (!which){
        float s = enc_bih[g];
        for (int e=0;e<64;++e) s += enc_emb[v*64+e]*enc_wih[g*64+e];
        te[r] = s;
    } else {
        float s = dec_bih[g];
        for (int e=0;e<64;++e) s += dec_emb[v*64+e]*dec_wih[g*128+64+e];
        td[r] = s;
    }
}

// pack w_hh (768x256) into MFMA B-fragment layout, bf16.
// frag elem: bpack[((nt*8+kt)*64+lane)*8+j] = w[n*256+k], n=nt*16+(lane&15), k=kt*32+(lane>>4)*8+j
__global__ __launch_bounds__(256) void k_pack(
    const float* __restrict__ whh_e, const float* __restrict__ whh_d,
    unsigned short* __restrict__ bpe, unsigned short* __restrict__ bpd)
{
    int id = blockIdx.x*256 + threadIdx.x;
    if (id >= 2*196608) return;
    int which = id / 196608, e = id % 196608;
    int j = e & 7, lane = (e>>3)&63, kt = (e>>9)&7, nt = e>>12;
    int k = kt*32 + (lane>>4)*8 + j, n = nt*16 + (lane&15);
    const float* w = which ? whh_d : whh_e;
    (which ? bpd : bpe)[e] = f2bf(w[n*256+k]);
}

__global__ __launch_bounds__(256) void k_pack_out(
    const float* __restrict__ w_out, unsigned short* __restrict__ bpo)
{
    int id = blockIdx.x*256 + threadIdx.x;
    if (id >= 16384) return;
    int j = id & 7, lane = (id>>3)&63, kt = (id>>9)&7, nt = id>>12;
    int k = kt*32 + (lane>>4)*8 + j, n = nt*16 + (lane&15);
    bpo[id] = f2bf(n < V_ ? w_out[n*256+k] : 0.0f);
}

// ---------------- GRU recurrence (persistent per-block over time) ----------------
// 16 batch rows/block, 8 waves. Wave w owns i-tiles {w, w+8}; gates at n-tiles {j,16+j,32+j}.
template<int DEC>
__global__ __launch_bounds__(512) void k_gru(
    const int* __restrict__ x, const float* __restrict__ table,
    const unsigned short* __restrict__ bpack, const float* __restrict__ bhh,
    const float* __restrict__ h0, const float* __restrict__ zvec,
    float* __restrict__ h_last, unsigned short* __restrict__ outs)
{
    const int Tn = DEC ? (T_-1) : T_;
    __shared__ unsigned short hbuf[2][16*H_];
    __shared__ int toks[16*T_];
    __shared__ float zvs[DEC ? 16*768 : 1];

    const int tid = threadIdx.x;
    const int w = tid>>6, lane = tid&63, lr = lane&15, lp = lane>>4;
    const int b0 = blockIdx.x*16;
    const bf16x8* bp = (const bf16x8*)bpack;

    float hreg[2][4];
    float bh[2][3];
    #pragma unroll
    for (int ji=0; ji<2; ++ji){
        int j = w + 8*ji, col = j*16 + lr;
        #pragma unroll
        for (int g=0; g<3; ++g) bh[ji][g] = bhh[g*H_ + col];
        #pragma unroll
        for (int q=0; q<4; ++q){
            int row = lp*4+q;
            float hv = DEC ? h0[(size_t)(b0+row)*H_ + col] : 0.0f;
            hreg[ji][q] = hv;
            hbuf[0][row*H_ + (col ^ ((row&7)<<3))] = f2bf(hv);
        }
    }
    for (int i=tid; i<16*T_; i+=512) toks[i] = x[(size_t)(b0 + (i>>6))*T_ + (i&63)];
    if (DEC){
        for (int i=tid; i<16*768; i+=512) zvs[i] = zvec[(size_t)b0*768 + i];
    }
    __syncthreads();

    for (int t=0; t<Tn; ++t){
        const int cur = t&1, nxt = cur^1;
        bf16x8 a[8];
        #pragma unroll
        for (int kt=0; kt<8; ++kt){
            int k0 = kt*32 + lp*8;
            a[kt] = *(const bf16x8*)&hbuf[cur][lr*H_ + (k0 ^ ((lr&7)<<3))];
        }
        int tok[4];
        #pragma unroll
        for (int q=0; q<4; ++q) tok[q] = toks[(lp*4+q)*T_ + t];

        #pragma unroll
        for (int ji=0; ji<2; ++ji){
            int j = w + 8*ji, col = j*16 + lr;
            floatx4 ar = {0,0,0,0}, az = {0,0,0,0}, an = {0,0,0,0};
            #pragma unroll
            for (int kt=0; kt<8; ++kt){
                ar = __builtin_amdgcn_mfma_f32_16x16x32_bf16(a[kt], bp[(( 0+j)*8+kt)*64+lane], ar, 0,0,0);
                az = __builtin_amdgcn_mfma_f32_16x16x32_bf16(a[kt], bp[((16+j)*8+kt)*64+lane], az, 0,0,0);
                an = __builtin_amdgcn_mfma_f32_16x16x32_bf16(a[kt], bp[((32+j)*8+kt)*64+lane], an, 0,0,0);
            }
            #pragma unroll
            for (int q=0; q<4; ++q){
                int row = lp*4+q;
                const float* tb = table + (size_t)tok[q]*(3*H_);
                float xr = tb[col], xz = tb[H_+col], xn = tb[2*H_+col];
                if (DEC){
                    const float* zr = &zvs[row*768];
                    xr += zr[col]; xz += zr[H_+col]; xn += zr[2*H_+col];
                }
                float rg = sigm(xr + ar[q] + bh[ji][0]);
                float zg = sigm(xz + az[q] + bh[ji][1]);
                float ng = tanh_fast(xn + rg*(an[q] + bh[ji][2]));
                float hv = (1.0f-zg)*ng + zg*hreg[ji][q];
                hreg[ji][q] = hv;
                unsigned short hb = f2bf(hv);
                hbuf[nxt][row*H_ + (col ^ ((row&7)<<3))] = hb;
                if (DEC) outs[((size_t)(b0+row)*(T_-1) + t)*H_ + col] = hb;
            }
        }
        __syncthreads();
    }
    if (!DEC){
        #pragma unroll
        for (int ji=0; ji<2; ++ji){
            int col = (w+8*ji)*16 + lr;
            #pragma unroll
            for (int q=0; q<4; ++q){
                int row = lp*4+q;
                h_last[(size_t)(b0+row)*H_ + col] = hreg[ji][q];
            }
        }
    }
}

// ---------------- latent: mu/logvar/toq, KL, VQ argmin, Q, zcat ----------------
__global__ __launch_bounds__(256) void k_latent(
    const float* __restrict__ hlast,
    const float* __restrict__ w_mu, const float* __restrict__ b_mu,
    const float* __restrict__ w_std, const float* __restrict__ b_std,
    const float* __restrict__ w_q, const float* __restrict__ b_q,
    const float* __restrict__ cb,
    float* __restrict__ zcat, float* __restrict__ pKL, float* __restrict__ pQ,
    float* __restrict__ out_idx)
{
    __shared__ float hs[8][H_];
    __shared__ float mu8[8][Z_], lv8[8][Z_], tq8[8][Z_];
    __shared__ float cbs[256*Z_];
    __shared__ float red[256];
    __shared__ int redi[256];
    const int tid = threadIdx.x;
    const int b0 = blockIdx.x*8;

    for (int i=tid; i<8*H_; i+=256) hs[i>>8][i&255] = hlast[(size_t)(b0+(i>>8))*H_ + (i&255)];
    __syncthreads();

    for (int id=tid; id<768; id+=256){
        int o = id % 96, bb = id / 96;
        int which = o>>5, zi = o&31;
        const float* wm = which==0 ? w_mu : (which==1 ? w_std : w_q);
        const float* bm = which==0 ? b_mu : (which==1 ? b_std : b_q);
        float s = bm[zi];
        const float* h = hs[bb];
        for (int k=0;k<H_;++k) s += h[k]*wm[zi*H_+k];
        if (which==0) mu8[bb][zi]=s; else if (which==1) lv8[bb][zi]=s; else tq8[bb][zi]=s;
    }
    __syncthreads();

    { // KL partial
        int bb = tid>>5, zi = tid&31;
        float m = mu8[bb][zi], l = lv8[bb][zi];
        red[tid] = 0.5f*(m*m + __expf(l) - l - 1.0f);
    }
    __syncthreads();
    for (int s=128; s>0; s>>=1){ if (tid<s) red[tid]+=red[tid+s]; __syncthreads(); }
    if (tid==0) pKL[blockIdx.x] = red[0];
    __syncthreads();

    // VQ argmin: thread group of 32 per batch row; first-index tie-break
    const int bb = tid>>5, c = tid&31;
    float best = 3.4e38f; int bi = 0;
    for (int ch=0; ch<4; ++ch){
        int kb = ch*256;
        int kn = (K_ - kb) < 256 ? (K_ - kb) : 256;
        for (int i=tid; i<kn*Z_; i+=256) cbs[i] = cb[(size_t)kb*Z_ + i];
        __syncthreads();
        for (int jj=0; jj<8; ++jj){
            int k = c + 32*(ch*8+jj);
            if (k < K_){
                const float* cv = &cbs[(k-kb)*Z_];
                float d = 0.f;
                #pragma unroll
                for (int ci=0; ci<Z_; ++ci){ float df = tq8[bb][ci]-cv[ci]; d += df*df; }
                if (d < best){ best = d; bi = k; }
            }
        }
        __syncthreads();
    }
    red[tid]=best; redi[tid]=bi;
    __syncthreads();
    for (int s=16; s>0; s>>=1){
        if ((tid&31) < s){
            float ob = red[tid+s]; int oi = redi[tid+s];
            if (ob < red[tid] || (ob == red[tid] && oi < redi[tid])){ red[tid]=ob; redi[tid]=oi; }
        }
        __syncthreads();
    }
    if (tid < 8){
        int k = redi[tid*32];
        float s = 0.f;
        for (int ci=0; ci<Z_; ++ci){ float df = cb[(size_t)k*Z_+ci]-tq8[tid][ci]; s += df*df; }
        red[tid] = s * (0.3f/32.0f);   // (COMMIT_W + QUANT_W) * mean
        out_idx[b0+tid] = (float)k;
    }
    __syncthreads();
    if (tid==0){ float q=0; for (int i=0;i<8;++i) q+=red[i]; pQ[blockIdx.x]=q; }
    for (int i=tid; i<8*64; i+=256){
        int bb2 = i>>6, cc = i&63;
        int k = redi[bb2*32];
        zcat[(size_t)(b0+bb2)*64 + cc] = (cc < Z_) ? cb[(size_t)k*Z_+cc] : mu8[bb2][cc-Z_];
    }
}

// ---------------- hidden = zcat@w_up.T + b_up ; zvec = zcat@dec_wih[:, :64].T ----------------
__global__ __launch_bounds__(256) void k_mid(
    const float* __restrict__ zcat, const float* __restrict__ w_up, const float* __restrict__ b_up,
    const float* __restrict__ dwih, float* __restrict__ hidden, float* __restrict__ zvec)
{
    __shared__ float zs[8][64];
    const int tid = threadIdx.x;
    const int b0 = blockIdx.x*8;
    for (int i=tid;i<512;i+=256) zs[i>>6][i&63] = zcat[(size_t)(b0+(i>>6))*64 + (i&63)];
    __syncthreads();
    for (int id=tid; id<8*1024; id+=256){
        int bb = id>>10, o = id&1023;
        const float* zr = zs[bb];
        if (o < H_){
            float s = b_up[o];
            const float* wr = w_up + o*64;
            for (int ck=0;ck<64;++ck) s += zr[ck]*wr[ck];
            hidden[(size_t)(b0+bb)*H_ + o] = s;
        } else {
            int g = o - H_;
            float s = 0.f;
            const float* wr = dwih + (size_t)g*128;
            for (int ck=0;ck<64;++ck) s += zr[ck]*wr[ck];
            zvec[(size_t)(b0+bb)*768 + g] = s;
        }
    }
}

// ---------------- logits + log_softmax + loss ----------------
__global__ __launch_bounds__(256) void k_loss(
    const unsigned short* __restrict__ outs, const unsigned short* __restrict__ bpo,
    const float* __restrict__ b_out, const int* __restrict__ x,
    float* __restrict__ pred, float* __restrict__ pXL, float* __restrict__ pNP)
{
    __shared__ float ll[16][64];
    __shared__ float bo[64];
    __shared__ float redf[256], redn[256];
    const int tid = threadIdx.x, w = tid>>6, lane = tid&63, lr = lane&15, lp = lane>>4;
    const bf16x8* bpofr = (const bf16x8*)bpo;
    bf16x8 bw[8];
    #pragma unroll
    for (int kt=0;kt<8;++kt) bw[kt] = bpofr[(w*8+kt)*64 + lane];
    if (tid < 64) bo[tid] = (tid < V_) ? b_out[tid] : 0.0f;
    float xl = 0.f, npn = 0.f;
    for (int cc=0; cc<4; ++cc){
        int row0 = (blockIdx.x*4 + cc)*16;
        floatx4 acc = {0,0,0,0};
        #pragma unroll
        for (int kt=0;kt<8;++kt){
            int k0 = kt*32 + lp*8;
            bf16x8 av = *(const bf16x8*)&outs[(size_t)(row0+lr)*H_ + k0];
            acc = __builtin_amdgcn_mfma_f32_16x16x32_bf16(av, bw[kt], acc, 0,0,0);
        }
        __syncthreads();
        #pragma unroll
        for (int q=0;q<4;++q) ll[lp*4+q][w*16+lr] = acc[q];
        __syncthreads();
        if (tid < 16){
            int row = row0 + tid;
            int b = row/63, tt = row - b*63;
            int tgt = x[(size_t)b*T_ + tt + 1];
            float m = -3.4e38f; int am = 0;
            for (int v=0;v<V_;++v){ float lv = ll[tid][v]+bo[v]; if (lv > m){ m = lv; am = v; } }
            float ssum = 0.f;
            for (int v=0;v<V_;++v) ssum += __expf(ll[tid][v]+bo[v]-m);
            float lse = m + __logf(ssum);
            pred[row] = (float)am;
            if (tgt != 0){ xl += ll[tid][tgt]+bo[tgt]-lse; npn += 1.f; }
        }
    }
    redf[tid]=xl; redn[tid]=npn;
    __syncthreads();
    for (int s=128;s>0;s>>=1){ if (tid<s){ redf[tid]+=redf[tid+s]; redn[tid]+=redn[tid+s]; } __syncthreads(); }
    if (tid==0){ pXL[blockIdx.x]=redf[0]; pNP[blockIdx.x]=redn[0]; }
}

// ---------------- final reduce ----------------
__global__ __launch_bounds__(256) void k_reduce(
    const float* __restrict__ pKL, const float* __restrict__ pQ,
    const float* __restrict__ pXL, const float* __restrict__ pNP, float* __restrict__ dout)
{
    __shared__ float r[256];
    const int tid = threadIdx.x;
    r[tid] = pKL[tid]; __syncthreads();
    for (int s=128;s>0;s>>=1){ if (tid<s) r[tid]+=r[tid+s]; __syncthreads(); }
    if (tid==0) dout[129026] = r[0];
    __syncthreads();
    r[tid] = pQ[tid]; __syncthreads();
    for (int s=128;s>0;s>>=1){ if (tid<s) r[tid]+=r[tid+s]; __syncthreads(); }
    if (tid==0) dout[129027] = r[0];
    __syncthreads();
    float a = 0.f;
    for (int i=tid;i<2016;i+=256) a += pXL[i];
    r[tid] = a; __syncthreads();
    for (int s=128;s>0;s>>=1){ if (tid<s) r[tid]+=r[tid+s]; __syncthreads(); }
    if (tid==0) dout[0] = -r[0];
    __syncthreads();
    a = 0.f;
    for (int i=tid;i<2016;i+=256) a += pNP[i];
    r[tid] = a; __syncthreads();
    for (int s=128;s>0;s>>=1){ if (tid<s) r[tid]+=r[tid+s]; __syncthreads(); }
    if (tid==0) dout[1] = r[0];
}

extern "C" void kernel_launch(void* const* d_in, const int* in_sizes, int n_in,
                              void* d_out, int out_size, void* d_ws, size_t ws_size,
                              hipStream_t stream)
{
    const int*   x       = (const int*)  d_in[0];
    const float* enc_emb = (const float*)d_in[1];
    const float* enc_wih = (const float*)d_in[2];
    const float* enc_whh = (const float*)d_in[3];
    const float* enc_bih = (const float*)d_in[4];
    const float* enc_bhh = (const float*)d_in[5];
    const float* w_mu    = (const float*)d_in[6];
    const float* b_mu    = (const float*)d_in[7];
    const float* w_std   = (const float*)d_in[8];
    const float* b_std   = (const float*)d_in[9];
    const float* w_q     = (const float*)d_in[10];
    const float* b_q     = (const float*)d_in[11];
    const float* w_up    = (const float*)d_in[12];
    const float* b_up    = (const float*)d_in[13];
    const float* cb      = (const float*)d_in[14];
    const float* dec_emb = (const float*)d_in[15];
    const float* dec_wih = (const float*)d_in[16];
    const float* dec_whh = (const float*)d_in[17];
    const float* dec_bih = (const float*)d_in[18];
    const float* dec_bhh = (const float*)d_in[19];
    const float* w_out   = (const float*)d_in[20];
    const float* b_out   = (const float*)d_in[21];

    float* ws = (float*)d_ws;
    float* te   = ws + 0;         // 39168
    float* td   = ws + 39168;     // 39168
    unsigned short* bpe  = (unsigned short*)(ws + 78336);   // 196608 ush
    unsigned short* bpd  = (unsigned short*)(ws + 176640);  // 196608 ush
    unsigned short* bpo  = (unsigned short*)(ws + 274944);  // 16384 ush
    float* hl   = ws + 283136;    // 524288
    float* zc   = ws + 807424;    // 131072
    float* hid  = ws + 938496;    // 524288
    float* zv   = ws + 1462784;   // 1572864
    unsigned short* outs = (unsigned short*)(ws + 3035648); // 33030144 ush
    float* pKL  = ws + 19550720;  // 256
    float* pQ   = ws + 19550976;  // 256
    float* pXL  = ws + 19551232;  // 2016
    float* pNP  = ws + 19553248;  // 2016

    float* dout = (float*)d_out;

    k_tables<<<306,256,0,stream>>>(enc_emb, enc_wih, enc_bih, dec_emb, dec_wih, dec_bih, te, td);
    k_pack<<<1536,256,0,stream>>>(enc_whh, dec_whh, bpe, bpd);
    k_pack_out<<<64,256,0,stream>>>(w_out, bpo);
    k_gru<0><<<128,512,0,stream>>>(x, te, bpe, enc_bhh, nullptr, nullptr, hl, nullptr);
    k_latent<<<256,256,0,stream>>>(hl, w_mu,b_mu,w_std,b_std,w_q,b_q, cb, zc, pKL, pQ, dout + 129028);
    k_mid<<<256,256,0,stream>>>(zc, w_up, b_up, dec_wih, hid, zv);
    k_gru<1><<<128,512,0,stream>>>(x, td, bpd, dec_bhh, hid, zv, nullptr, outs);
    k_loss<<<2016,256,0,stream>>>(outs, bpo, b_out, x, dout + 2, pXL, pNP);
    k_reduce<<<1,256,0,stream>>>(pKL, pQ, pXL, pNP, dout);
}

// Round 2
// 402.320 us; speedup vs baseline: 2.0036x; 2.0036x over previous
//
#include <hip/hip_runtime.h>
#include <hip/hip_bf16.h>

#define B_ 2048
#define T_ 64
#define H_ 256
#define V_ 51
#define Z_ 32
#define K_ 1000

typedef __bf16 bf16x8 __attribute__((ext_vector_type(8)));
typedef float floatx4 __attribute__((ext_vector_type(4)));

__device__ inline unsigned short f2bf(float f){
    unsigned int u = __float_as_uint(f);
    u += 0x7fffu + ((u >> 16) & 1u);
    return (unsigned short)(u >> 16);
}
__device__ inline float sigm(float x){
    float e = __expf(-x);
    return __builtin_amdgcn_rcpf(1.0f + e);
}
__device__ inline float tanh_fast(float x){
    float e = __expf(-2.0f*x);          // x->+inf: e->0 -> 1 ; x->-inf: e->inf -> rcp 0 -> -1
    return __builtin_fmaf(-2.0f, __builtin_amdgcn_rcpf(1.0f + e), 1.0f);
}
__device__ inline float permlane_merge(float d, float s){
    // after: lanes 0..31 keep d's low half, lanes 32..63 get s's low half
    asm volatile("v_permlane32_swap_b32 %0, %1" : "+v"(d), "+v"(s));
    return d;
}

// ---------------- prep kernels ----------------
// packed tables: tp[(v*256+col)*4 + g] = bf16( emb[v]·wih_g_col + bih[g*256+col] + (g<2 ? bhh[g*256+col] : 0) )
__global__ __launch_bounds__(256) void k_tables(
    const float* __restrict__ enc_emb, const float* __restrict__ enc_wih, const float* __restrict__ enc_bih,
    const float* __restrict__ enc_bhh,
    const float* __restrict__ dec_emb, const float* __restrict__ dec_wih, const float* __restrict__ dec_bih,
    const float* __restrict__ dec_bhh,
    unsigned short* __restrict__ tep, unsigned short* __restrict__ tdp)
{
    int id = blockIdx.x*256 + threadIdx.x;
    if (id >= 2*V_*768) return;
    int which = id / (V_*768), r = id % (V_*768);
    int v = r / 768, g = r % 768;
    int gate = g >> 8, col = g & 255;
    float s;
    if (!which){
        s = enc_bih[g] + (gate < 2 ? enc_bhh[g] : 0.0f);
        for (int e=0;e<64;++e) s += enc_emb[v*64+e]*enc_wih[g*64+e];
        tep[(v*256+col)*4 + gate] = f2bf(s);
    } else {
        s = dec_bih[g] + (gate < 2 ? dec_bhh[g] : 0.0f);
        for (int e=0;e<64;++e) s += dec_emb[v*64+e]*dec_wih[g*128+64+e];
        tdp[(v*256+col)*4 + gate] = f2bf(s);
    }
}

// pack w_hh (768x256) into MFMA B-fragment layout, bf16.
__global__ __launch_bounds__(256) void k_pack(
    const float* __restrict__ whh_e, const float* __restrict__ whh_d,
    unsigned short* __restrict__ bpe, unsigned short* __restrict__ bpd)
{
    int id = blockIdx.x*256 + threadIdx.x;
    if (id >= 2*196608) return;
    int which = id / 196608, e = id % 196608;
    int j = e & 7, lane = (e>>3)&63, kt = (e>>9)&7, nt = e>>12;
    int k = kt*32 + (lane>>4)*8 + j, n = nt*16 + (lane&15);
    const float* wmat = which ? whh_d : whh_e;
    (which ? bpd : bpe)[e] = f2bf(wmat[n*256+k]);
}

__global__ __launch_bounds__(256) void k_pack_out(
    const float* __restrict__ w_out, unsigned short* __restrict__ bpo)
{
    int id = blockIdx.x*256 + threadIdx.x;
    if (id >= 16384) return;
    int j = id & 7, lane = (id>>3)&63, kt = (id>>9)&7, nt = id>>12;
    int k = kt*32 + (lane>>4)*8 + j, n = nt*16 + (lane&15);
    bpo[id] = f2bf(n < V_ ? w_out[n*256+k] : 0.0f);
}

// ---------------- GRU recurrence: 256 blocks x 8 batch rows, 8 waves ----------------
template<int DEC>
__global__ __launch_bounds__(512) void k_gru(
    const int* __restrict__ x, const unsigned short* __restrict__ tblg,
    const unsigned short* __restrict__ bpack, const float* __restrict__ bhh,
    const float* __restrict__ h0, const unsigned short* __restrict__ zvp,
    float* __restrict__ h_last, unsigned short* __restrict__ outs)
{
    const int Tn = DEC ? (T_-1) : T_;
    __shared__ alignas(16) unsigned short tbl[V_*1024];      // [v][col][4] bf16, 102KB
    __shared__ alignas(16) unsigned short hbuf[2*4096];      // [buf][16 rows][256] bf16, swizzled
    __shared__ alignas(16) unsigned short zvs[DEC ? 8192 : 8]; // [row][col][4] bf16
    __shared__ unsigned int tpk[T_][2];                      // 4 packed tokens per (t, rowgroup)

    const int tid = threadIdx.x;
    const int w = tid>>6, lane = tid&63, lr = lane&15, lp = lane>>4;
    const int b0 = blockIdx.x*8;
    const int jm = w + ((lane>=32)?8:0);
    const int col_m = jm*16 + lr;          // merged-layout output column
    const int rbase = (lp&1)*4;            // merged-layout row base (q adds 0..3)
    const int colm4 = col_m*4;

    // ---- hoist all 48 weight fragments into registers (192 VGPR) ----
    const bf16x8* bp = (const bf16x8*)bpack;
    bf16x8 wf[2][3][8];
    #pragma unroll
    for (int ji=0; ji<2; ++ji)
      #pragma unroll
      for (int g=0; g<3; ++g)
        #pragma unroll
        for (int kt=0; kt<8; ++kt)
            wf[ji][g][kt] = bp[(((g*16) + w + 8*ji)*8 + kt)*64 + lane];

    // ---- stage table into LDS ----
    {
        uint4* d4 = (uint4*)tbl; const uint4* s4 = (const uint4*)tblg;
        for (int i=tid; i<(V_*1024)/8; i+=512) d4[i] = s4[i];
    }
    if (DEC){
        uint4* d4 = (uint4*)zvs; const uint4* s4 = (const uint4*)(zvp + (size_t)b0*1024);
        for (int i=tid; i<1024; i+=512) d4[i] = s4[i];
    }
    // zero rows 8..15 of both h buffers (never written in loop)
    for (int i=tid; i<4096; i+=512){
        int bufi = i>>11, rr = 8 + ((i>>8)&7), c = i&255;
        hbuf[bufi*4096 + rr*256 + c] = 0;
    }
    // pack tokens: tpk[t][g] = bytes of x[b0+4g+0..3][t]
    if (tid < 128){
        int t = tid>>1, g = tid&1;
        unsigned int p = 0;
        #pragma unroll
        for (int r=0;r<4;++r) p |= ((unsigned int)x[(size_t)(b0 + g*4 + r)*T_ + t]) << (8*r);
        tpk[t][g] = p;
    }

    // ---- per-lane state ----
    const float bhn = bhh[2*H_ + col_m];
    float hreg[4];
    int waddr[4];          // hbuf write ushort-index (constant per lane)
    unsigned int ooff[4];  // outs element offsets (DEC)
    #pragma unroll
    for (int q=0; q<4; ++q){
        int row = rbase + q;
        float hv = DEC ? h0[(size_t)(b0+row)*H_ + col_m] : 0.0f;
        hreg[q] = hv;
        waddr[q] = row*256 + (col_m ^ (row<<3));
        hbuf[waddr[q]] = f2bf(hv);
        if (DEC) ooff[q] = (unsigned int)(((b0+row)*(T_-1))*H_ + col_m);
    }
    // a-frag read ushort-index bases (kt pairs: +64 ushorts per pair)
    const int s3 = (lr&7)<<3, lpb = lp*8;
    const int aidx0 = lr*256 + (lpb ^ s3);
    const int aidx1 = lr*256 + ((32 + lpb) ^ s3);
    const int zb = rbase*1024 + colm4;
    __syncthreads();

    auto step = [&](int t, int cur) {
        const int nxt = cur^1;
        unsigned int tp = tpk[t][lp&1];
        // ---- MFMA phase (standard fragment layout) ----
        floatx4 acc[2][3] = {};
        bf16x8 aA = *(const bf16x8*)&hbuf[(cur<<12) + aidx0];
        bf16x8 aB = *(const bf16x8*)&hbuf[(cur<<12) + aidx1];
        bf16x8 aC = *(const bf16x8*)&hbuf[(cur<<12) + aidx0 + 64];
        #pragma unroll
        for (int kt=0; kt<8; ++kt){
            bf16x8 av = (kt%3==0) ? aA : ((kt%3==1) ? aB : aC);
            #pragma unroll
            for (int ji=0; ji<2; ++ji)
              #pragma unroll
              for (int g=0; g<3; ++g)
                acc[ji][g] = __builtin_amdgcn_mfma_f32_16x16x32_bf16(av, wf[ji][g][kt], acc[ji][g], 0,0,0);
            if (kt+3 < 8){
                int nk = kt+3;
                bf16x8 nv = *(const bf16x8*)&hbuf[(cur<<12) + ((nk&1)?aidx1:aidx0) + ((nk>>1)<<6)];
                if (kt%3==0) aA = nv; else if (kt%3==1) aB = nv; else aC = nv;
            }
        }
        // ---- merge to all-lane layout + gates ----
        #pragma unroll
        for (int q=0; q<4; ++q){
            float mr = permlane_merge(acc[0][0][q], acc[1][0][q]);
            float mz = permlane_merge(acc[0][1][q], acc[1][1][q]);
            float mn = permlane_merge(acc[0][2][q], acc[1][2][q]);
            int tok = (tp >> (8*q)) & 255;
            uint2 tv = *(const uint2*)&tbl[(tok<<10) + colm4];
            float xr = __uint_as_float(tv.x << 16);
            float xz = __uint_as_float(tv.x & 0xffff0000u);
            float xn = __uint_as_float(tv.y << 16);
            if (DEC){
                uint2 zv = *(const uint2*)&zvs[zb + q*1024];
                xr += __uint_as_float(zv.x << 16);
                xz += __uint_as_float(zv.x & 0xffff0000u);
                xn += __uint_as_float(zv.y << 16);
            }
            float rg = sigm(xr + mr);
            float zg = sigm(xz + mz);
            float ng = tanh_fast(__builtin_fmaf(rg, mn + bhn, xn));
            float hv = __builtin_fmaf(zg, hreg[q] - ng, ng);
            hreg[q] = hv;
            unsigned short hb = f2bf(hv);
            hbuf[(nxt<<12) + waddr[q]] = hb;
            if (DEC){ outs[ooff[q]] = hb; ooff[q] += 256; }
        }
        __syncthreads();
    };

    for (int t=0; t+1<Tn; t+=2){ step(t,0); step(t+1,1); }
    if (Tn & 1) step(Tn-1, 0);

    if (!DEC){
        #pragma unroll
        for (int q=0; q<4; ++q)
            h_last[(size_t)(b0+rbase+q)*H_ + col_m] = hreg[q];
    }
}

// ---------------- latent: mu/logvar/toq, KL, VQ argmin, Q, zcat ----------------
__global__ __launch_bounds__(256) void k_latent(
    const float* __restrict__ hlast,
    const float* __restrict__ w_mu, const float* __restrict__ b_mu,
    const float* __restrict__ w_std, const float* __restrict__ b_std,
    const float* __restrict__ w_q, const float* __restrict__ b_q,
    const float* __restrict__ cb,
    float* __restrict__ zcat, float* __restrict__ pKL, float* __restrict__ pQ,
    float* __restrict__ out_idx)
{
    __shared__ float hs[8][H_];
    __shared__ float mu8[8][Z_], lv8[8][Z_], tq8[8][Z_];
    __shared__ float cbs[256*Z_];
    __shared__ float red[256];
    __shared__ int redi[256];
    const int tid = threadIdx.x;
    const int b0 = blockIdx.x*8;

    for (int i=tid; i<8*H_; i+=256) hs[i>>8][i&255] = hlast[(size_t)(b0+(i>>8))*H_ + (i&255)];
    __syncthreads();

    for (int id=tid; id<768; id+=256){
        int o = id % 96, bb = id / 96;
        int which = o>>5, zi = o&31;
        const float* wm = which==0 ? w_mu : (which==1 ? w_std : w_q);
        const float* bm = which==0 ? b_mu : (which==1 ? b_std : b_q);
        float s = bm[zi];
        const float* h = hs[bb];
        for (int k=0;k<H_;++k) s += h[k]*wm[zi*H_+k];
        if (which==0) mu8[bb][zi]=s; else if (which==1) lv8[bb][zi]=s; else tq8[bb][zi]=s;
    }
    __syncthreads();

    { // KL partial
        int bb = tid>>5, zi = tid&31;
        float m = mu8[bb][zi], l = lv8[bb][zi];
        red[tid] = 0.5f*(m*m + __expf(l) - l - 1.0f);
    }
    __syncthreads();
    for (int s=128; s>0; s>>=1){ if (tid<s) red[tid]+=red[tid+s]; __syncthreads(); }
    if (tid==0) pKL[blockIdx.x] = red[0];
    __syncthreads();

    // VQ argmin: 32 threads per batch row; first-index tie-break
    const int bb = tid>>5, c = tid&31;
    float best = 3.4e38f; int bi = 0;
    for (int ch=0; ch<4; ++ch){
        int kb = ch*256;
        int kn = (K_ - kb) < 256 ? (K_ - kb) : 256;
        for (int i=tid; i<kn*Z_; i+=256) cbs[i] = cb[(size_t)kb*Z_ + i];
        __syncthreads();
        for (int jj=0; jj<8; ++jj){
            int k = c + 32*(ch*8+jj);
            if (k < K_){
                const float* cv = &cbs[(k-kb)*Z_];
                float d = 0.f;
                #pragma unroll
                for (int ci=0; ci<Z_; ++ci){ float df = tq8[bb][ci]-cv[ci]; d += df*df; }
                if (d < best){ best = d; bi = k; }
            }
        }
        __syncthreads();
    }
    red[tid]=best; redi[tid]=bi;
    __syncthreads();
    for (int s=16; s>0; s>>=1){
        if ((tid&31) < s){
            float ob = red[tid+s]; int oi = redi[tid+s];
            if (ob < red[tid] || (ob == red[tid] && oi < redi[tid])){ red[tid]=ob; redi[tid]=oi; }
        }
        __syncthreads();
    }
    if (tid < 8){
        int k = redi[tid*32];
        float s = 0.f;
        for (int ci=0; ci<Z_; ++ci){ float df = cb[(size_t)k*Z_+ci]-tq8[tid][ci]; s += df*df; }
        red[tid] = s * (0.3f/32.0f);
        out_idx[b0+tid] = (float)k;
    }
    __syncthreads();
    if (tid==0){ float q=0; for (int i=0;i<8;++i) q+=red[i]; pQ[blockIdx.x]=q; }
    for (int i=tid; i<8*64; i+=256){
        int bb2 = i>>6, cc = i&63;
        int k = redi[bb2*32];
        zcat[(size_t)(b0+bb2)*64 + cc] = (cc < Z_) ? cb[(size_t)k*Z_+cc] : mu8[bb2][cc-Z_];
    }
}

// ---------------- hidden = zcat@w_up.T + b_up ; zvp = packed bf16 zcat@dec_wih[:, :64].T ----------------
__global__ __launch_bounds__(256) void k_mid(
    const float* __restrict__ zcat, const float* __restrict__ w_up, const float* __restrict__ b_up,
    const float* __restrict__ dwih, float* __restrict__ hidden, unsigned short* __restrict__ zvp)
{
    __shared__ float zs[8][64];
    const int tid = threadIdx.x;
    const int b0 = blockIdx.x*8;
    for (int i=tid;i<512;i+=256) zs[i>>6][i&63] = zcat[(size_t)(b0+(i>>6))*64 + (i&63)];
    __syncthreads();
    for (int id=tid; id<8*1024; id+=256){
        int bb = id>>10, o = id&1023;
        const float* zr = zs[bb];
        if (o < H_){
            float s = b_up[o];
            const float* wr = w_up + o*64;
            for (int ck=0;ck<64;++ck) s += zr[ck]*wr[ck];
            hidden[(size_t)(b0+bb)*H_ + o] = s;
        } else {
            int g = o - H_;
            int gate = g>>8, col = g&255;
            float s = 0.f;
            const float* wr = dwih + (size_t)g*128;
            for (int ck=0;ck<64;++ck) s += zr[ck]*wr[ck];
            zvp[((size_t)(b0+bb)*256 + col)*4 + gate] = f2bf(s);
        }
    }
}

// ---------------- logits + log_softmax + loss ----------------
__global__ __launch_bounds__(256) void k_loss(
    const unsigned short* __restrict__ outs, const unsigned short* __restrict__ bpo,
    const float* __restrict__ b_out, const int* __restrict__ x,
    float* __restrict__ pred, float* __restrict__ pXL, float* __restrict__ pNP)
{
    __shared__ float ll[16][64];
    __shared__ float bo[64];
    __shared__ float redf[256], redn[256];
    const int tid = threadIdx.x, w = tid>>6, lane = tid&63, lr = lane&15, lp = lane>>4;
    const bf16x8* bpofr = (const bf16x8*)bpo;
    bf16x8 bw[8];
    #pragma unroll
    for (int kt=0;kt<8;++kt) bw[kt] = bpofr[(w*8+kt)*64 + lane];
    if (tid < 64) bo[tid] = (tid < V_) ? b_out[tid] : 0.0f;
    float xl = 0.f, npn = 0.f;
    const int row = tid>>4, vl = tid&15;
    for (int cc=0; cc<4; ++cc){
        int row0 = (blockIdx.x*4 + cc)*16;
        floatx4 acc = {0,0,0,0};
        #pragma unroll
        for (int kt=0;kt<8;++kt){
            bf16x8 av = *(const bf16x8*)&outs[(size_t)(row0+lr)*H_ + kt*32 + lp*8];
            acc = __builtin_amdgcn_mfma_f32_16x16x32_bf16(av, bw[kt], acc, 0,0,0);
        }
        __syncthreads();
        #pragma unroll
        for (int q=0;q<4;++q) ll[lp*4+q][w*16+lr] = acc[q];
        __syncthreads();
        // wave-parallel softmax: 16 lanes per row
        float lv[4];
        #pragma unroll
        for (int k2=0;k2<4;++k2){
            int v = vl + 16*k2;
            lv[k2] = (v < V_) ? ll[row][v] + bo[v] : -3.4e38f;
        }
        float m = lv[0]; int am = vl;
        #pragma unroll
        for (int k2=1;k2<4;++k2){ if (lv[k2] > m){ m = lv[k2]; am = vl + 16*k2; } }
        #pragma unroll
        for (int off=1; off<16; off<<=1){
            float om = __shfl_xor(m, off, 16);
            int oa = __shfl_xor(am, off, 16);
            if (om > m || (om == m && oa < am)){ m = om; am = oa; }
        }
        float se = 0.f;
        #pragma unroll
        for (int k2=0;k2<4;++k2) se += __expf(lv[k2]-m);
        #pragma unroll
        for (int off=1; off<16; off<<=1) se += __shfl_xor(se, off, 16);
        if (vl == 0){
            int rowg = row0 + row;
            int b = rowg/63, tt = rowg - b*63;
            int tgt = x[(size_t)b*T_ + tt + 1];
            pred[rowg] = (float)am;
            if (tgt != 0){
                float lse = m + __logf(se);
                xl += ll[row][tgt] + bo[tgt] - lse;
                npn += 1.f;
            }
        }
    }
    redf[tid]=xl; redn[tid]=npn;
    __syncthreads();
    for (int s=128;s>0;s>>=1){ if (tid<s){ redf[tid]+=redf[tid+s]; redn[tid]+=redn[tid+s]; } __syncthreads(); }
    if (tid==0){ pXL[blockIdx.x]=redf[0]; pNP[blockIdx.x]=redn[0]; }
}

// ---------------- final reduce ----------------
__global__ __launch_bounds__(256) void k_reduce(
    const float* __restrict__ pKL, const float* __restrict__ pQ,
    const float* __restrict__ pXL, const float* __restrict__ pNP, float* __restrict__ dout)
{
    __shared__ float r[256];
    const int tid = threadIdx.x;
    r[tid] = pKL[tid]; __syncthreads();
    for (int s=128;s>0;s>>=1){ if (tid<s) r[tid]+=r[tid+s]; __syncthreads(); }
    if (tid==0) dout[129026] = r[0];
    __syncthreads();
    r[tid] = pQ[tid]; __syncthreads();
    for (int s=128;s>0;s>>=1){ if (tid<s) r[tid]+=r[tid+s]; __syncthreads(); }
    if (tid==0) dout[129027] = r[0];
    __syncthreads();
    float a = 0.f;
    for (int i=tid;i<2016;i+=256) a += pXL[i];
    r[tid] = a; __syncthreads();
    for (int s=128;s>0;s>>=1){ if (tid<s) r[tid]+=r[tid+s]; __syncthreads(); }
    if (tid==0) dout[0] = -r[0];
    __syncthreads();
    a = 0.f;
    for (int i=tid;i<2016;i+=256) a += pNP[i];
    r[tid] = a; __syncthreads();
    for (int s=128;s>0;s>>=1){ if (tid<s) r[tid]+=r[tid+s]; __syncthreads(); }
    if (tid==0) dout[1] = r[0];
}

extern "C" void kernel_launch(void* const* d_in, const int* in_sizes, int n_in,
                              void* d_out, int out_size, void* d_ws, size_t ws_size,
                              hipStream_t stream)
{
    const int*   x       = (const int*)  d_in[0];
    const float* enc_emb = (const float*)d_in[1];
    const float* enc_wih = (const float*)d_in[2];
    const float* enc_whh = (const float*)d_in[3];
    const float* enc_bih = (const float*)d_in[4];
    const float* enc_bhh = (const float*)d_in[5];
    const float* w_mu    = (const float*)d_in[6];
    const float* b_mu    = (const float*)d_in[7];
    const float* w_std   = (const float*)d_in[8];
    const float* b_std   = (const float*)d_in[9];
    const float* w_q     = (const float*)d_in[10];
    const float* b_q     = (const float*)d_in[11];
    const float* w_up    = (const float*)d_in[12];
    const float* b_up    = (const float*)d_in[13];
    const float* cb      = (const float*)d_in[14];
    const float* dec_emb = (const float*)d_in[15];
    const float* dec_wih = (const float*)d_in[16];
    const float* dec_whh = (const float*)d_in[17];
    const float* dec_bih = (const float*)d_in[18];
    const float* dec_bhh = (const float*)d_in[19];
    const float* w_out   = (const float*)d_in[20];
    const float* b_out   = (const float*)d_in[21];

    float* ws = (float*)d_ws;
    unsigned short* tep = (unsigned short*)(ws + 0);        // 52224 ush
    unsigned short* tdp = (unsigned short*)(ws + 26112);    // 52224 ush
    unsigned short* bpe = (unsigned short*)(ws + 52224);    // 196608 ush
    unsigned short* bpd = (unsigned short*)(ws + 150528);   // 196608 ush
    unsigned short* bpo = (unsigned short*)(ws + 248832);   // 16384 ush
    float* hl   = ws + 257024;    // 524288
    float* zc   = ws + 781312;    // 131072
    float* hid  = ws + 912384;    // 524288
    unsigned short* zvp  = (unsigned short*)(ws + 1436672); // 2097152 ush
    unsigned short* outs = (unsigned short*)(ws + 2485248); // 33030144 ush
    float* pKL  = ws + 19000320;  // 256
    float* pQ   = ws + 19000576;  // 256
    float* pXL  = ws + 19000832;  // 2016
    float* pNP  = ws + 19002848;  // 2016

    float* dout = (float*)d_out;

    k_tables<<<306,256,0,stream>>>(enc_emb, enc_wih, enc_bih, enc_bhh,
                                   dec_emb, dec_wih, dec_bih, dec_bhh, tep, tdp);
    k_pack<<<1536,256,0,stream>>>(enc_whh, dec_whh, bpe, bpd);
    k_pack_out<<<64,256,0,stream>>>(w_out, bpo);
    k_gru<0><<<256,512,0,stream>>>(x, tep, bpe, enc_bhh, nullptr, nullptr, hl, nullptr);
    k_latent<<<256,256,0,stream>>>(hl, w_mu,b_mu,w_std,b_std,w_q,b_q, cb, zc, pKL, pQ, dout + 129028);
    k_mid<<<256,256,0,stream>>>(zc, w_up, b_up, dec_wih, hid, zvp);
    k_gru<1><<<256,512,0,stream>>>(x, tdp, bpd, dec_bhh, hid, zvp, nullptr, outs);
    k_loss<<<2016,256,0,stream>>>(outs, bpo, b_out, x, dout + 2, pXL, pNP);
    k_reduce<<<1,256,0,stream>>>(pKL, pQ, pXL, pNP, dout);
}

// Round 3
// 355.282 us; speedup vs baseline: 2.2688x; 1.1324x over previous
//
#include <hip/hip_runtime.h>
#include <hip/hip_bf16.h>

#define B_ 2048
#define T_ 64
#define H_ 256
#define V_ 51
#define Z_ 32
#define K_ 1000

typedef __bf16 bf16x8 __attribute__((ext_vector_type(8)));
typedef float floatx4 __attribute__((ext_vector_type(4)));

__device__ inline unsigned short f2bf(float f){
    unsigned int u = __float_as_uint(f);
    u += 0x7fffu + ((u >> 16) & 1u);
    return (unsigned short)(u >> 16);
}
__device__ inline float sigm(float x){
    float e = __expf(-x);
    return __builtin_amdgcn_rcpf(1.0f + e);
}
__device__ inline float tanh_fast(float x){
    float e = __expf(-2.0f*x);
    return __builtin_fmaf(-2.0f, __builtin_amdgcn_rcpf(1.0f + e), 1.0f);
}
__device__ inline float permlane_merge(float d, float s){
    asm volatile("v_permlane32_swap_b32 %0, %1" : "+v"(d), "+v"(s));
    return d;
}

// ---------------- prep kernels ----------------
__global__ __launch_bounds__(256) void k_tables(
    const float* __restrict__ enc_emb, const float* __restrict__ enc_wih, const float* __restrict__ enc_bih,
    const float* __restrict__ enc_bhh,
    const float* __restrict__ dec_emb, const float* __restrict__ dec_wih, const float* __restrict__ dec_bih,
    const float* __restrict__ dec_bhh,
    unsigned short* __restrict__ tep, unsigned short* __restrict__ tdp)
{
    int id = blockIdx.x*256 + threadIdx.x;
    if (id >= 2*V_*768) return;
    int which = id / (V_*768), r = id % (V_*768);
    int v = r / 768, g = r % 768;
    int gate = g >> 8, col = g & 255;
    float s;
    if (!which){
        s = enc_bih[g] + (gate < 2 ? enc_bhh[g] : 0.0f);
        for (int e=0;e<64;++e) s += enc_emb[v*64+e]*enc_wih[g*64+e];
        tep[(v*256+col)*4 + gate] = f2bf(s);
    } else {
        s = dec_bih[g] + (gate < 2 ? dec_bhh[g] : 0.0f);
        for (int e=0;e<64;++e) s += dec_emb[v*64+e]*dec_wih[g*128+64+e];
        tdp[(v*256+col)*4 + gate] = f2bf(s);
    }
}

__global__ __launch_bounds__(256) void k_pack(
    const float* __restrict__ whh_e, const float* __restrict__ whh_d,
    unsigned short* __restrict__ bpe, unsigned short* __restrict__ bpd)
{
    int id = blockIdx.x*256 + threadIdx.x;
    if (id >= 2*196608) return;
    int which = id / 196608, e = id % 196608;
    int j = e & 7, lane = (e>>3)&63, kt = (e>>9)&7, nt = e>>12;
    int k = kt*32 + (lane>>4)*8 + j, n = nt*16 + (lane&15);
    const float* wmat = which ? whh_d : whh_e;
    (which ? bpd : bpe)[e] = f2bf(wmat[n*256+k]);
}

__global__ __launch_bounds__(256) void k_pack_out(
    const float* __restrict__ w_out, unsigned short* __restrict__ bpo)
{
    int id = blockIdx.x*256 + threadIdx.x;
    if (id >= 16384) return;
    int j = id & 7, lane = (id>>3)&63, kt = (id>>9)&7, nt = id>>12;
    int k = kt*32 + (lane>>4)*8 + j, n = nt*16 + (lane&15);
    bpo[id] = f2bf(n < V_ ? w_out[n*256+k] : 0.0f);
}

// ---------------- GRU recurrence: 256 blocks x 8 batch rows, 8 waves ----------------
// __launch_bounds__(512, 2): 2 waves/EU -> 256-VGPR cap; weight frags stay register-resident.
template<int DEC>
__global__ __launch_bounds__(512, 2) void k_gru(
    const int* __restrict__ x, const unsigned short* __restrict__ tblg,
    const unsigned short* __restrict__ bpack, const float* __restrict__ bhh,
    const float* __restrict__ h0, const unsigned short* __restrict__ zvp,
    float* __restrict__ h_last, unsigned short* __restrict__ outs)
{
    const int Tn = DEC ? (T_-1) : T_;
    __shared__ alignas(16) unsigned short tbl[V_*1024];        // [v][col][4] bf16
    __shared__ alignas(16) unsigned short hbuf[2*4096];        // [buf][16 rows][256] bf16, swizzled
    __shared__ alignas(16) unsigned short zvs[DEC ? 8192 : 8]; // [row][col][4] bf16
    __shared__ unsigned int tpk[T_][2];

    const int tid = threadIdx.x;
    const int w = tid>>6, lane = tid&63, lr = lane&15, lp = lane>>4;
    const int b0 = blockIdx.x*8;
    const int jm = w + ((lane>=32)?8:0);
    const int col_m = jm*16 + lr;
    const int rbase = (lp&1)*4;
    const int colm4 = col_m*4;

    // ---- hoist all 48 weight fragments into registers (192 VGPR) ----
    const bf16x8* bp = (const bf16x8*)bpack;
    bf16x8 wf[2][3][8];
    #pragma unroll
    for (int ji=0; ji<2; ++ji)
      #pragma unroll
      for (int g=0; g<3; ++g)
        #pragma unroll
        for (int kt=0; kt<8; ++kt)
            wf[ji][g][kt] = bp[(((g*16) + w + 8*ji)*8 + kt)*64 + lane];

    // ---- stage table into LDS ----
    {
        uint4* d4 = (uint4*)tbl; const uint4* s4 = (const uint4*)tblg;
        for (int i=tid; i<(V_*1024)/8; i+=512) d4[i] = s4[i];
    }
    if (DEC){
        uint4* d4 = (uint4*)zvs; const uint4* s4 = (const uint4*)(zvp + (size_t)b0*1024);
        for (int i=tid; i<1024; i+=512) d4[i] = s4[i];
    }
    for (int i=tid; i<4096; i+=512){
        int bufi = i>>11, rr = 8 + ((i>>8)&7), c = i&255;
        hbuf[bufi*4096 + rr*256 + c] = 0;
    }
    if (tid < 128){
        int t = tid>>1, g = tid&1;
        unsigned int p = 0;
        #pragma unroll
        for (int r=0;r<4;++r) p |= ((unsigned int)x[(size_t)(b0 + g*4 + r)*T_ + t]) << (8*r);
        tpk[t][g] = p;
    }

    // ---- per-lane state ----
    const float bhn = bhh[2*H_ + col_m];
    float hreg[4];
    int waddr[4];
    #pragma unroll
    for (int q=0; q<4; ++q){
        int row = rbase + q;
        float hv = DEC ? h0[(size_t)(b0+row)*H_ + col_m] : 0.0f;
        hreg[q] = hv;
        waddr[q] = row*256 + (col_m ^ (row<<3));
        hbuf[waddr[q]] = f2bf(hv);
    }
    const int s3 = (lr&7)<<3, lpb = lp*8;
    const int aidx0 = lr*256 + (lpb ^ s3);
    const int aidx1 = lr*256 + ((32 + lpb) ^ s3);
    const int zb = rbase*1024 + colm4;
    // coalesced outs-copy addressing (DEC): wave w copies hbuf row w
    const int crow = w, cc4 = (lane)<<2;
    const int csrc = crow*256 + (cc4 ^ (crow<<3));
    unsigned short* cdst0 = DEC ? (outs + ((size_t)(b0+crow)*(T_-1))*H_ + cc4) : nullptr;
    __syncthreads();

    auto step = [&](int t, int cur) {
        const int nxt = cur^1;
        unsigned int tp = tpk[t][lp&1];
        floatx4 acc[2][3] = {};
        bf16x8 aA = *(const bf16x8*)&hbuf[(cur<<12) + aidx0];
        bf16x8 aB = *(const bf16x8*)&hbuf[(cur<<12) + aidx1];
        bf16x8 aC = *(const bf16x8*)&hbuf[(cur<<12) + aidx0 + 64];
        #pragma unroll
        for (int kt=0; kt<8; ++kt){
            bf16x8 av = (kt%3==0) ? aA : ((kt%3==1) ? aB : aC);
            #pragma unroll
            for (int ji=0; ji<2; ++ji)
              #pragma unroll
              for (int g=0; g<3; ++g)
                acc[ji][g] = __builtin_amdgcn_mfma_f32_16x16x32_bf16(av, wf[ji][g][kt], acc[ji][g], 0,0,0);
            if (kt+3 < 8){
                int nk = kt+3;
                bf16x8 nv = *(const bf16x8*)&hbuf[(cur<<12) + ((nk&1)?aidx1:aidx0) + ((nk>>1)<<6)];
                if (kt%3==0) aA = nv; else if (kt%3==1) aB = nv; else aC = nv;
            }
        }
        #pragma unroll
        for (int q=0; q<4; ++q){
            float mr = permlane_merge(acc[0][0][q], acc[1][0][q]);
            float mz = permlane_merge(acc[0][1][q], acc[1][1][q]);
            float mn = permlane_merge(acc[0][2][q], acc[1][2][q]);
            int tok = (tp >> (8*q)) & 255;
            uint2 tv = *(const uint2*)&tbl[(tok<<10) + colm4];
            float xr = __uint_as_float(tv.x << 16);
            float xz = __uint_as_float(tv.x & 0xffff0000u);
            float xn = __uint_as_float(tv.y << 16);
            if (DEC){
                uint2 zv = *(const uint2*)&zvs[zb + q*1024];
                xr += __uint_as_float(zv.x << 16);
                xz += __uint_as_float(zv.x & 0xffff0000u);
                xn += __uint_as_float(zv.y << 16);
            }
            float rg = sigm(xr + mr);
            float zg = sigm(xz + mz);
            float ng = tanh_fast(__builtin_fmaf(rg, mn + bhn, xn));
            float hv = __builtin_fmaf(zg, hreg[q] - ng, ng);
            hreg[q] = hv;
            hbuf[(nxt<<12) + waddr[q]] = f2bf(hv);
        }
        __syncthreads();
        if (DEC){
            // coalesced copy of completed step: wave w stores row w, 512B contiguous
            uint2 v = *(const uint2*)&hbuf[(nxt<<12) + csrc];
            *(uint2*)(cdst0 + (size_t)t*H_) = v;
        }
    };

    for (int t=0; t+1<Tn; t+=2){ step(t,0); step(t+1,1); }
    if (Tn & 1) step(Tn-1, 0);

    if (!DEC){
        #pragma unroll
        for (int q=0; q<4; ++q)
            h_last[(size_t)(b0+rbase+q)*H_ + col_m] = hreg[q];
    }
}

// ---------------- latent: mu/logvar/toq, KL, VQ argmin, Q, zcat ----------------
__global__ __launch_bounds__(256) void k_latent(
    const float* __restrict__ hlast,
    const float* __restrict__ w_mu, const float* __restrict__ b_mu,
    const float* __restrict__ w_std, const float* __restrict__ b_std,
    const float* __restrict__ w_q, const float* __restrict__ b_q,
    const float* __restrict__ cb,
    float* __restrict__ zcat, float* __restrict__ pKL, float* __restrict__ pQ,
    float* __restrict__ out_idx)
{
    __shared__ float hs[8][H_];
    __shared__ float mu8[8][Z_], lv8[8][Z_], tq8[8][Z_];
    __shared__ float cbs[256*Z_];
    __shared__ float red[256];
    __shared__ int redi[256];
    const int tid = threadIdx.x;
    const int b0 = blockIdx.x*8;

    for (int i=tid; i<8*H_; i+=256) hs[i>>8][i&255] = hlast[(size_t)(b0+(i>>8))*H_ + (i&255)];
    __syncthreads();

    for (int id=tid; id<768; id+=256){
        int o = id % 96, bb = id / 96;
        int which = o>>5, zi = o&31;
        const float* wm = which==0 ? w_mu : (which==1 ? w_std : w_q);
        const float* bm = which==0 ? b_mu : (which==1 ? b_std : b_q);
        float s = bm[zi];
        const float* h = hs[bb];
        for (int k=0;k<H_;++k) s += h[k]*wm[zi*H_+k];
        if (which==0) mu8[bb][zi]=s; else if (which==1) lv8[bb][zi]=s; else tq8[bb][zi]=s;
    }
    __syncthreads();

    {
        int bb = tid>>5, zi = tid&31;
        float m = mu8[bb][zi], l = lv8[bb][zi];
        red[tid] = 0.5f*(m*m + __expf(l) - l - 1.0f);
    }
    __syncthreads();
    for (int s=128; s>0; s>>=1){ if (tid<s) red[tid]+=red[tid+s]; __syncthreads(); }
    if (tid==0) pKL[blockIdx.x] = red[0];
    __syncthreads();

    const int bb = tid>>5, c = tid&31;
    float best = 3.4e38f; int bi = 0;
    for (int ch=0; ch<4; ++ch){
        int kb = ch*256;
        int kn = (K_ - kb) < 256 ? (K_ - kb) : 256;
        for (int i=tid; i<kn*Z_; i+=256) cbs[i] = cb[(size_t)kb*Z_ + i];
        __syncthreads();
        for (int jj=0; jj<8; ++jj){
            int k = c + 32*(ch*8+jj);
            if (k < K_){
                const float* cv = &cbs[(k-kb)*Z_];
                float d = 0.f;
                #pragma unroll
                for (int ci=0; ci<Z_; ++ci){ float df = tq8[bb][ci]-cv[ci]; d += df*df; }
                if (d < best){ best = d; bi = k; }
            }
        }
        __syncthreads();
    }
    red[tid]=best; redi[tid]=bi;
    __syncthreads();
    for (int s=16; s>0; s>>=1){
        if ((tid&31) < s){
            float ob = red[tid+s]; int oi = redi[tid+s];
            if (ob < red[tid] || (ob == red[tid] && oi < redi[tid])){ red[tid]=ob; redi[tid]=oi; }
        }
        __syncthreads();
    }
    if (tid < 8){
        int k = redi[tid*32];
        float s = 0.f;
        for (int ci=0; ci<Z_; ++ci){ float df = cb[(size_t)k*Z_+ci]-tq8[tid][ci]; s += df*df; }
        red[tid] = s * (0.3f/32.0f);
        out_idx[b0+tid] = (float)k;
    }
    __syncthreads();
    if (tid==0){ float q=0; for (int i=0;i<8;++i) q+=red[i]; pQ[blockIdx.x]=q; }
    for (int i=tid; i<8*64; i+=256){
        int bb2 = i>>6, cc = i&63;
        int k = redi[bb2*32];
        zcat[(size_t)(b0+bb2)*64 + cc] = (cc < Z_) ? cb[(size_t)k*Z_+cc] : mu8[bb2][cc-Z_];
    }
}

// ---------------- hidden = zcat@w_up.T + b_up ; zvp = packed bf16 zcat@dec_wih[:, :64].T ----------------
__global__ __launch_bounds__(256) void k_mid(
    const float* __restrict__ zcat, const float* __restrict__ w_up, const float* __restrict__ b_up,
    const float* __restrict__ dwih, float* __restrict__ hidden, unsigned short* __restrict__ zvp)
{
    __shared__ float zs[8][64];
    const int tid = threadIdx.x;
    const int b0 = blockIdx.x*8;
    for (int i=tid;i<512;i+=256) zs[i>>6][i&63] = zcat[(size_t)(b0+(i>>6))*64 + (i&63)];
    __syncthreads();
    for (int id=tid; id<8*1024; id+=256){
        int bb = id>>10, o = id&1023;
        const float* zr = zs[bb];
        if (o < H_){
            float s = b_up[o];
            const float* wr = w_up + o*64;
            for (int ck=0;ck<64;++ck) s += zr[ck]*wr[ck];
            hidden[(size_t)(b0+bb)*H_ + o] = s;
        } else {
            int g = o - H_;
            int gate = g>>8, col = g&255;
            float s = 0.f;
            const float* wr = dwih + (size_t)g*128;
            for (int ck=0;ck<64;++ck) s += zr[ck]*wr[ck];
            zvp[((size_t)(b0+bb)*256 + col)*4 + gate] = f2bf(s);
        }
    }
}

// ---------------- logits + log_softmax + loss ----------------
__global__ __launch_bounds__(256) void k_loss(
    const unsigned short* __restrict__ outs, const unsigned short* __restrict__ bpo,
    const float* __restrict__ b_out, const int* __restrict__ x,
    float* __restrict__ pred, float* __restrict__ pXL, float* __restrict__ pNP)
{
    __shared__ float ll[16][64];
    __shared__ float bo[64];
    __shared__ float redf[256], redn[256];
    const int tid = threadIdx.x, w = tid>>6, lane = tid&63, lr = lane&15, lp = lane>>4;
    const bf16x8* bpofr = (const bf16x8*)bpo;
    bf16x8 bw[8];
    #pragma unroll
    for (int kt=0;kt<8;++kt) bw[kt] = bpofr[(w*8+kt)*64 + lane];
    if (tid < 64) bo[tid] = (tid < V_) ? b_out[tid] : 0.0f;
    float xl = 0.f, npn = 0.f;
    const int row = tid>>4, vl = tid&15;
    for (int cc=0; cc<4; ++cc){
        int row0 = (blockIdx.x*4 + cc)*16;
        floatx4 acc = {0,0,0,0};
        #pragma unroll
        for (int kt=0;kt<8;++kt){
            bf16x8 av = *(const bf16x8*)&outs[(size_t)(row0+lr)*H_ + kt*32 + lp*8];
            acc = __builtin_amdgcn_mfma_f32_16x16x32_bf16(av, bw[kt], acc, 0,0,0);
        }
        __syncthreads();
        #pragma unroll
        for (int q=0;q<4;++q) ll[lp*4+q][w*16+lr] = acc[q];
        __syncthreads();
        float lv[4];
        #pragma unroll
        for (int k2=0;k2<4;++k2){
            int v = vl + 16*k2;
            lv[k2] = (v < V_) ? ll[row][v] + bo[v] : -3.4e38f;
        }
        float m = lv[0]; int am = vl;
        #pragma unroll
        for (int k2=1;k2<4;++k2){ if (lv[k2] > m){ m = lv[k2]; am = vl + 16*k2; } }
        #pragma unroll
        for (int off=1; off<16; off<<=1){
            float om = __shfl_xor(m, off, 16);
            int oa = __shfl_xor(am, off, 16);
            if (om > m || (om == m && oa < am)){ m = om; am = oa; }
        }
        float se = 0.f;
        #pragma unroll
        for (int k2=0;k2<4;++k2) se += __expf(lv[k2]-m);
        #pragma unroll
        for (int off=1; off<16; off<<=1) se += __shfl_xor(se, off, 16);
        if (vl == 0){
            int rowg = row0 + row;
            int b = rowg/63, tt = rowg - b*63;
            int tgt = x[(size_t)b*T_ + tt + 1];
            pred[rowg] = (float)am;
            if (tgt != 0){
                float lse = m + __logf(se);
                xl += ll[row][tgt] + bo[tgt] - lse;
                npn += 1.f;
            }
        }
    }
    redf[tid]=xl; redn[tid]=npn;
    __syncthreads();
    for (int s=128;s>0;s>>=1){ if (tid<s){ redf[tid]+=redf[tid+s]; redn[tid]+=redn[tid+s]; } __syncthreads(); }
    if (tid==0){ pXL[blockIdx.x]=redf[0]; pNP[blockIdx.x]=redn[0]; }
}

// ---------------- final reduce ----------------
__global__ __launch_bounds__(256) void k_reduce(
    const float* __restrict__ pKL, const float* __restrict__ pQ,
    const float* __restrict__ pXL, const float* __restrict__ pNP, float* __restrict__ dout)
{
    __shared__ float r[256];
    const int tid = threadIdx.x;
    r[tid] = pKL[tid]; __syncthreads();
    for (int s=128;s>0;s>>=1){ if (tid<s) r[tid]+=r[tid+s]; __syncthreads(); }
    if (tid==0) dout[129026] = r[0];
    __syncthreads();
    r[tid] = pQ[tid]; __syncthreads();
    for (int s=128;s>0;s>>=1){ if (tid<s) r[tid]+=r[tid+s]; __syncthreads(); }
    if (tid==0) dout[129027] = r[0];
    __syncthreads();
    float a = 0.f;
    for (int i=tid;i<2016;i+=256) a += pXL[i];
    r[tid] = a; __syncthreads();
    for (int s=128;s>0;s>>=1){ if (tid<s) r[tid]+=r[tid+s]; __syncthreads(); }
    if (tid==0) dout[0] = -r[0];
    __syncthreads();
    a = 0.f;
    for (int i=tid;i<2016;i+=256) a += pNP[i];
    r[tid] = a; __syncthreads();
    for (int s=128;s>0;s>>=1){ if (tid<s) r[tid]+=r[tid+s]; __syncthreads(); }
    if (tid==0) dout[1] = r[0];
}

extern "C" void kernel_launch(void* const* d_in, const int* in_sizes, int n_in,
                              void* d_out, int out_size, void* d_ws, size_t ws_size,
                              hipStream_t stream)
{
    const int*   x       = (const int*)  d_in[0];
    const float* enc_emb = (const float*)d_in[1];
    const float* enc_wih = (const float*)d_in[2];
    const float* enc_whh = (const float*)d_in[3];
    const float* enc_bih = (const float*)d_in[4];
    const float* enc_bhh = (const float*)d_in[5];
    const float* w_mu    = (const float*)d_in[6];
    const float* b_mu    = (const float*)d_in[7];
    const float* w_std   = (const float*)d_in[8];
    const float* b_std   = (const float*)d_in[9];
    const float* w_q     = (const float*)d_in[10];
    const float* b_q     = (const float*)d_in[11];
    const float* w_up    = (const float*)d_in[12];
    const float* b_up    = (const float*)d_in[13];
    const float* cb      = (const float*)d_in[14];
    const float* dec_emb = (const float*)d_in[15];
    const float* dec_wih = (const float*)d_in[16];
    const float* dec_whh = (const float*)d_in[17];
    const float* dec_bih = (const float*)d_in[18];
    const float* dec_bhh = (const float*)d_in[19];
    const float* w_out   = (const float*)d_in[20];
    const float* b_out   = (const float*)d_in[21];

    float* ws = (float*)d_ws;
    unsigned short* tep = (unsigned short*)(ws + 0);        // 52224 ush
    unsigned short* tdp = (unsigned short*)(ws + 26112);    // 52224 ush
    unsigned short* bpe = (unsigned short*)(ws + 52224);    // 196608 ush
    unsigned short* bpd = (unsigned short*)(ws + 150528);   // 196608 ush
    unsigned short* bpo = (unsigned short*)(ws + 248832);   // 16384 ush
    float* hl   = ws + 257024;    // 524288
    float* zc   = ws + 781312;    // 131072
    float* hid  = ws + 912384;    // 524288
    unsigned short* zvp  = (unsigned short*)(ws + 1436672); // 2097152 ush
    unsigned short* outs = (unsigned short*)(ws + 2485248); // 33030144 ush
    float* pKL  = ws + 19000320;  // 256
    float* pQ   = ws + 19000576;  // 256
    float* pXL  = ws + 19000832;  // 2016
    float* pNP  = ws + 19002848;  // 2016

    float* dout = (float*)d_out;

    k_tables<<<306,256,0,stream>>>(enc_emb, enc_wih, enc_bih, enc_bhh,
                                   dec_emb, dec_wih, dec_bih, dec_bhh, tep, tdp);
    k_pack<<<1536,256,0,stream>>>(enc_whh, dec_whh, bpe, bpd);
    k_pack_out<<<64,256,0,stream>>>(w_out, bpo);
    k_gru<0><<<256,512,0,stream>>>(x, tep, bpe, enc_bhh, nullptr, nullptr, hl, nullptr);
    k_latent<<<256,256,0,stream>>>(hl, w_mu,b_mu,w_std,b_std,w_q,b_q, cb, zc, pKL, pQ, dout + 129028);
    k_mid<<<256,256,0,stream>>>(zc, w_up, b_up, dec_wih, hid, zvp);
    k_gru<1><<<256,512,0,stream>>>(x, tdp, bpd, dec_bhh, hid, zvp, nullptr, outs);
    k_loss<<<2016,256,0,stream>>>(outs, bpo, b_out, x, dout + 2, pXL, pNP);
    k_reduce<<<1,256,0,stream>>>(pKL, pQ, pXL, pNP, dout);
}